// Round 2
// baseline (1466.178 us; speedup 1.0000x reference)
//
#include <hip/hip_runtime.h>

constexpr int kB = 128;
constexpr int kT = 1024;
constexpr int kI = 64;
constexpr int kH = 512;
constexpr int kO = 32;
constexpr float kTau = 0.2f;
constexpr float kNoise = 0.05f;

__device__ __forceinline__ float fast_tanh(float x) {
    // tanh(x) = 1 - 2/(e^{2x}+1); exact limits at +-inf, ~1e-7 abs error.
    float e = __expf(2.0f * x);
    return 1.0f - 2.0f * __builtin_amdgcn_rcpf(e + 1.0f);
}

// Raw barrier with LDS-only drain: global loads/stores stay in flight across
// it (unlike __syncthreads, which drains vmcnt(0) and serializes prefetches).
#define BARW() do { asm volatile("s_waitcnt lgkmcnt(0)" ::: "memory"); \
                    __builtin_amdgcn_s_barrier();                      \
                    asm volatile("" ::: "memory"); } while (0)

// DPP-based 64-lane sum (VALU pipe only, no LDS). Result valid in lane 63.
template <int CTRL, int RMASK>
__device__ __forceinline__ float dpp_add(float s) {
    return s + __int_as_float(__builtin_amdgcn_update_dpp(
        0, __float_as_int(s), CTRL, RMASK, 0xf, true));
}
__device__ __forceinline__ float wave_sum64_lane63(float s) {
    s = dpp_add<0x111, 0xf>(s);   // row_shr:1
    s = dpp_add<0x112, 0xf>(s);   // row_shr:2
    s = dpp_add<0x114, 0xf>(s);   // row_shr:4
    s = dpp_add<0x118, 0xf>(s);   // row_shr:8  -> lane 15/31/47/63 = row sums
    s = dpp_add<0x142, 0xa>(s);   // row_bcast15 into rows 1,3
    s = dpp_add<0x143, 0xc>(s);   // row_bcast31 into rows 2,3 -> lane 63 total
    return s;
}

// One block per batch row. 512 threads = one per hidden unit h.
// Per step: A: 6 rank-product stores; bar; B: waves 0-5 reduce their column
// (8 strided b32 reads + DPP butterfly, result stored from lane 63); bar;
// C: broadcast-read res, per-thread 64-FMA input projection from the
// register-held wave-uniform u row (hides the res read latency), state
// update, traj store, and register prefetch of u[t+1]/noise[t+2].
__global__ __launch_bounds__(512, 2) void scan_kernel(
    const float* __restrict__ u, const float* __restrict__ x0,
    const float* __restrict__ noise, const float* __restrict__ Win_w,
    const float* __restrict__ Win_b, const float* __restrict__ M_rnn,
    const float* __restrict__ N_rnn, const float* __restrict__ L_tb,
    const float* __restrict__ M_tb, const float* __restrict__ N_tb,
    float* __restrict__ traj, float* __restrict__ xfin)
{
    const int b    = blockIdx.x;
    const int h    = threadIdx.x;
    const int wid  = h >> 6;
    const int lane = h & 63;

    __shared__ float red[6 * kH];            // column-major rank products
    __shared__ __align__(16) float res[8];   // 6 reduced scalars

    // Per-thread input-projection row, pinned into VGPRs (compiler otherwise
    // rematerializes the loads inside the loop).
    float W[kI];
    #pragma unroll
    for (int i = 0; i < kI; i += 4) {
        float4 w = *(const float4*)&Win_w[h * kI + i];
        W[i] = w.x; W[i + 1] = w.y; W[i + 2] = w.z; W[i + 3] = w.w;
    }
    #pragma unroll
    for (int i = 0; i < kI; ++i) asm volatile("" : "+v"(W[i]));

    const float wb  = Win_b[h];
    const float Nr0 = N_rnn[h * 2], Nr1 = N_rnn[h * 2 + 1];
    const float Mt0 = M_tb[h * 2],  Mt1 = M_tb[h * 2 + 1];
    const float Nt0 = N_tb[h * 2],  Nt1 = N_tb[h * 2 + 1];
    const float sc_rnn = 1.0f / (float)kH;
    const float sc_tb  = 1.0f / ((float)kH * (float)kH);
    const float Mr0 = M_rnn[h * 2] * sc_rnn, Mr1 = M_rnn[h * 2 + 1] * sc_rnn;
    const float Lt0 = L_tb[h * 2] * sc_tb,   Lt1 = L_tb[h * 2 + 1] * sc_tb;

    float x = x0[b * kH + h];

    const float* up  = u + (size_t)b * kT * kI;
    const float* nzp = noise + (size_t)b * kH + h;     // noise[t][b][h]
    float* tp = traj + (size_t)b * kT * kH + h;        // traj[b][t][h]

    // u[t] held wave-uniform in registers (scalar/broadcast loads).
    float4 ur[16];
    {
        const float4* u4 = (const float4*)up;
        #pragma unroll
        for (int i = 0; i < 16; ++i) ur[i] = u4[i];
    }
    float nzA = nzp[0];
    float nzB = nzp[(size_t)kB * kH];

    auto step = [&](int t, float& nzC) {
        // ---- phase A: rank products ----
        float r = fast_tanh(x);
        red[0 * kH + h] = r * Nr0;
        red[1 * kH + h] = r * Nr1;
        red[2 * kH + h] = r * Mt0;
        red[3 * kH + h] = r * Mt1;
        red[4 * kH + h] = r * Nt0;
        red[5 * kH + h] = r * Nt1;
        BARW();
        // ---- phase B: column reductions (waves 0-5), DPP butterfly ----
        if (wid < 6) {
            const float* c = red + wid * kH + lane;
            float s0 = c[0]   + c[64];
            float s1 = c[128] + c[192];
            float s2 = c[256] + c[320];
            float s3 = c[384] + c[448];
            float s  = (s0 + s1) + (s2 + s3);
            s = wave_sum64_lane63(s);
            if (lane == 63) res[wid] = s;
        }
        BARW();
        // ---- phase C ----
        float4 r4 = *(const float4*)&res[0];   // a0,a1,m0,m1 (latency ~120cy)
        float2 r2 = *(const float2*)&res[4];   // n0,n1
        // ip FMAs execute under the res-read shadow (ur loaded last step).
        float ip = wb;
        #pragma unroll
        for (int i = 0; i < 16; ++i) {
            ip += ur[i].x * W[4 * i]     + ur[i].y * W[4 * i + 1]
                + ur[i].z * W[4 * i + 2] + ur[i].w * W[4 * i + 3];
        }
        // prefetch u[t+1] into the (now consumed) register buffer
        {
            int tn = (t + 1 < kT) ? t + 1 : kT - 1;
            const float4* u4 = (const float4*)(up + (size_t)tn * kI);
            #pragma unroll
            for (int i = 0; i < 16; ++i) ur[i] = u4[i];
        }
        float rec = r4.x * Mr0 + r4.y * Mr1
                  + (r4.z * r2.x) * Lt0 + (r4.w * r2.y) * Lt1 + ip;
        x = (1.0f - kTau) * x + kNoise * nzC + kTau * rec;
        tp[(size_t)t * kH] = x;
        int t2 = (t + 2 < kT) ? t + 2 : kT - 1;   // noise prefetch, distance 2
        nzC = nzp[(size_t)t2 * kB * kH];
    };

    for (int t = 0; t < kT; t += 2) {
        step(t, nzA);
        step(t + 1, nzB);
    }
    xfin[b * kH + h] = x;
}

// out[row][o] = sum_h tanh(traj[row][h]) * Wout_w[o][h] + Wout_b[o]
// 512 blocks x 256 threads; 256 rows/block; 16 chunks of 32 h.
// As staged transposed [h][row] (coalesced global read, tanh at load),
// Ws staged [h][o]. Thread computes 4 rows x 8 o; inner reads are b128,
// <=2-way bank aliasing (free). VALU/LDS balanced, ~2 blocks/CU.
constexpr int R_BLK = 256;
constexpr int H_CHK = 32;
constexpr int AS_LD = 260;   // pad: keeps rows 16B-aligned, reads 2-way

__global__ __launch_bounds__(256, 2) void out_kernel(
    const float* __restrict__ traj, const float* __restrict__ Wout_w,
    const float* __restrict__ Wout_b, float* __restrict__ out)
{
    __shared__ float As[H_CHK][AS_LD];   // 33.3 KB, [h][row]
    __shared__ float Ws[H_CHK][36];      // 4.6 KB,  [h][o]

    const int tid = threadIdx.x;
    const size_t row0 = (size_t)blockIdx.x * R_BLK;
    const int og = tid & 3;          // o = og*8 .. og*8+7
    const int rg = tid >> 2;         // rows rg*4 .. rg*4+3

    float acc[4][8];
    #pragma unroll
    for (int k = 0; k < 4; ++k)
        #pragma unroll
        for (int j = 0; j < 8; ++j) acc[k][j] = 0.f;

    const int lr = tid >> 3;         // staging row within 8-float4 groups
    const int lc4 = tid & 7;         // staging float4-col (h dir)
    const int wo = tid >> 3;         // Ws staging: o
    const int wc = (tid & 7) * 4;    // Ws staging: h offset

    for (int ch = 0; ch < 16; ++ch) {
        const int hc = ch * H_CHK;
        // issue global loads to registers
        float4 a[8];
        #pragma unroll
        for (int j = 0; j < 8; ++j) {
            const int r = j * 32 + lr;
            a[j] = *(const float4*)&traj[(row0 + r) * kH + hc + lc4 * 4];
        }
        float4 w = *(const float4*)&Wout_w[wo * kH + hc + wc];
        __syncthreads();             // WAR: previous chunk's compute done
        #pragma unroll
        for (int j = 0; j < 8; ++j) {
            const int r = j * 32 + lr;
            As[lc4 * 4 + 0][r] = fast_tanh(a[j].x);
            As[lc4 * 4 + 1][r] = fast_tanh(a[j].y);
            As[lc4 * 4 + 2][r] = fast_tanh(a[j].z);
            As[lc4 * 4 + 3][r] = fast_tanh(a[j].w);
        }
        Ws[wc + 0][wo] = w.x;
        Ws[wc + 1][wo] = w.y;
        Ws[wc + 2][wo] = w.z;
        Ws[wc + 3][wo] = w.w;
        __syncthreads();
        #pragma unroll
        for (int hh = 0; hh < H_CHK; ++hh) {
            float4 av = *(const float4*)&As[hh][rg * 4];
            float4 w0 = *(const float4*)&Ws[hh][og * 8];
            float4 w1 = *(const float4*)&Ws[hh][og * 8 + 4];
            const float av4[4] = {av.x, av.y, av.z, av.w};
            const float wv[8]  = {w0.x, w0.y, w0.z, w0.w,
                                  w1.x, w1.y, w1.z, w1.w};
            #pragma unroll
            for (int k = 0; k < 4; ++k)
                #pragma unroll
                for (int j = 0; j < 8; ++j)
                    acc[k][j] += av4[k] * wv[j];
        }
    }

    #pragma unroll
    for (int k = 0; k < 4; ++k) {
        const size_t row = row0 + rg * 4 + k;
        float4 v0, v1;
        v0.x = acc[k][0] + Wout_b[og * 8 + 0];
        v0.y = acc[k][1] + Wout_b[og * 8 + 1];
        v0.z = acc[k][2] + Wout_b[og * 8 + 2];
        v0.w = acc[k][3] + Wout_b[og * 8 + 3];
        v1.x = acc[k][4] + Wout_b[og * 8 + 4];
        v1.y = acc[k][5] + Wout_b[og * 8 + 5];
        v1.z = acc[k][6] + Wout_b[og * 8 + 6];
        v1.w = acc[k][7] + Wout_b[og * 8 + 7];
        *(float4*)&out[row * kO + og * 8]     = v0;
        *(float4*)&out[row * kO + og * 8 + 4] = v1;
    }
}

extern "C" void kernel_launch(void* const* d_in, const int* in_sizes, int n_in,
                              void* d_out, int out_size, void* d_ws, size_t ws_size,
                              hipStream_t stream) {
    const float* u      = (const float*)d_in[0];
    const float* x0     = (const float*)d_in[1];
    const float* noise  = (const float*)d_in[2];
    const float* Win_w  = (const float*)d_in[3];
    const float* Win_b  = (const float*)d_in[4];
    const float* Wout_w = (const float*)d_in[5];
    const float* Wout_b = (const float*)d_in[6];
    const float* M_rnn  = (const float*)d_in[7];
    const float* N_rnn  = (const float*)d_in[8];
    const float* L_tb   = (const float*)d_in[9];
    const float* M_tb   = (const float*)d_in[10];
    const float* N_tb   = (const float*)d_in[11];

    float* out  = (float*)d_out;                       // [B,T,O]
    float* xfin = out + (size_t)kB * kT * kO;          // [B,H]
    float* traj = xfin + (size_t)kB * kH;              // [B,T,H]

    scan_kernel<<<dim3(kB), dim3(kH), 0, stream>>>(
        u, x0, noise, Win_w, Win_b, M_rnn, N_rnn, L_tb, M_tb, N_tb, traj, xfin);
    out_kernel<<<dim3((kB * kT) / R_BLK), dim3(256), 0, stream>>>(
        traj, Wout_w, Wout_b, out);
}

// Round 4
// 1427.176 us; speedup vs baseline: 1.0273x; 1.0273x over previous
//
#include <hip/hip_runtime.h>

constexpr int kB = 128;
constexpr int kT = 1024;
constexpr int kI = 64;
constexpr int kH = 512;
constexpr int kO = 32;
constexpr float kTau = 0.2f;
constexpr float kNoise = 0.05f;

__device__ __forceinline__ float fast_tanh(float x) {
    // tanh(x) = 1 - 2/(e^{2x}+1); exact limits at +-inf, ~1e-7 abs error.
    float e = __expf(2.0f * x);
    return 1.0f - 2.0f * __builtin_amdgcn_rcpf(e + 1.0f);
}

// Raw barrier with LDS-only drain: global loads/stores stay in flight across
// it. NOTE: any SMEM (s_load) traffic also counts in lgkmcnt — kernels using
// this must not keep s_load prefetches in flight across it (scan reads all
// uniforms into registers before the loop; in-loop loads are per-lane vector).
#define BARW() do { asm volatile("s_waitcnt lgkmcnt(0)" ::: "memory"); \
                    __builtin_amdgcn_s_barrier();                      \
                    asm volatile("" ::: "memory"); } while (0)

// One DPP-add reduction stage (VALU pipe, no LDS).
template <int CTRL, int RMASK>
__device__ __forceinline__ float dpp_add(float s) {
    return s + __int_as_float(__builtin_amdgcn_update_dpp(
        0, __float_as_int(s), CTRL, RMASK, 0xf, true));
}

// ---------------------------------------------------------------------------
// inp_kernel: traj[b][t][h] = kTau*(u[b,t,:]·Win_w[h,:] + Win_b[h])
//                           + kNoise*noise[t][b][h]
// The scan later reads this value at step t and overwrites the same address
// with x[t] (read-before-write within the owning thread) — no workspace.
// Block = 256 threads, each owns h = 2*tid, 2*tid+1 with tau-scaled Win rows
// held in VGPRs across ROWS_PB rows; u rows are block-uniform -> SMEM.
// ---------------------------------------------------------------------------
constexpr int ROWS_PB = 64;

__global__ __launch_bounds__(256, 2) void inp_kernel(
    const float* __restrict__ u, const float* __restrict__ Win_w,
    const float* __restrict__ Win_b, const float* __restrict__ noise,
    float* __restrict__ traj)
{
    const int tid = threadIdx.x;
    const int h2 = tid * 2;
    const size_t row0 = (size_t)blockIdx.x * ROWS_PB;

    float W0[kI], W1[kI];
    #pragma unroll
    for (int i = 0; i < kI; i += 4) {
        float4 a = *(const float4*)&Win_w[(size_t)h2 * kI + i];
        float4 c = *(const float4*)&Win_w[(size_t)(h2 + 1) * kI + i];
        W0[i] = a.x * kTau; W0[i + 1] = a.y * kTau;
        W0[i + 2] = a.z * kTau; W0[i + 3] = a.w * kTau;
        W1[i] = c.x * kTau; W1[i + 1] = c.y * kTau;
        W1[i + 2] = c.z * kTau; W1[i + 3] = c.w * kTau;
    }
    const float twb0 = Win_b[h2] * kTau;
    const float twb1 = Win_b[h2 + 1] * kTau;

    for (int r = 0; r < ROWS_PB; ++r) {
        const size_t row = row0 + r;
        const float* ur = u + row * kI;        // block-uniform -> SMEM
        float ip0 = twb0, ip1 = twb1;
        #pragma unroll
        for (int i = 0; i < kI; ++i) {
            float ui = ur[i];
            ip0 += ui * W0[i];
            ip1 += ui * W1[i];
        }
        const int t = (int)(row & (kT - 1));
        const int b = (int)(row >> 10);
        float2 nz = *(const float2*)&noise[((size_t)t * kB + b) * kH + h2];
        float2 c;
        c.x = ip0 + kNoise * nz.x;
        c.y = ip1 + kNoise * nz.y;
        *(float2*)&traj[row * kH + h2] = c;
    }
}

// ---------------------------------------------------------------------------
// scan_kernel: one block per batch row, 512 threads = one per hidden unit.
// Per step:
//   A: r=tanh(x); 6 rank products; 6 interleaved 6-stage DPP wave reductions
//      (pure VALU); lane 63 of each wave stores 6 partials -> pp[j*8+wid].
//   bar
//   B: wave 0 reads pp[lane] (48 valid), 3-stage DPP sum over groups of 8,
//      lanes 0,8,..,40 write res[0..5].
//   bar
//   C: broadcast-read res, combine with tau-folded weights, add the
//      precomputed c (dist-2 register prefetch via vmcnt, never drained),
//      store x to traj (same address c came from).
// LDS hazards: pp W->R crosses bar1, R->W crosses bar2 (reads drained by
// lgkmcnt(0) before the barrier); res W->R crosses bar2, R->W crosses the
// next step's bar1. All pairs barrier-separated.
// ---------------------------------------------------------------------------
__global__ __launch_bounds__(512, 2) void scan_kernel(
    const float* __restrict__ x0, const float* __restrict__ M_rnn,
    const float* __restrict__ N_rnn, const float* __restrict__ L_tb,
    const float* __restrict__ M_tb, const float* __restrict__ N_tb,
    float* __restrict__ traj, float* __restrict__ xfin)
{
    const int b    = blockIdx.x;
    const int h    = threadIdx.x;
    const int wid  = h >> 6;
    const int lane = h & 63;

    __shared__ float pp[64];                 // [j*8 + w], 48 used
    __shared__ __align__(16) float res[8];   // 6 reduced scalars

    const float Nr0 = N_rnn[h * 2], Nr1 = N_rnn[h * 2 + 1];
    const float Mt0 = M_tb[h * 2],  Mt1 = M_tb[h * 2 + 1];
    const float Nt0 = N_tb[h * 2],  Nt1 = N_tb[h * 2 + 1];
    const float sr = kTau / (float)kH;
    const float st = kTau / ((float)kH * (float)kH);
    const float tMr0 = M_rnn[h * 2] * sr, tMr1 = M_rnn[h * 2 + 1] * sr;
    const float tLt0 = L_tb[h * 2] * st,  tLt1 = L_tb[h * 2 + 1] * st;

    float x = x0[b * kH + h];
    float* tp = traj + (size_t)b * kT * kH + h;   // c read / x write

    float cA = tp[0];
    float cB = tp[kH];

    auto step = [&](int t, float& c) {
        // ---- phase A ----
        float r = fast_tanh(x);
        float s0 = r * Nr0, s1 = r * Nr1;
        float s2 = r * Mt0, s3 = r * Mt1;
        float s4 = r * Nt0, s5 = r * Nt1;
        #define STAGE(CTRL, MASK)                                   \
            s0 = dpp_add<CTRL, MASK>(s0); s1 = dpp_add<CTRL, MASK>(s1); \
            s2 = dpp_add<CTRL, MASK>(s2); s3 = dpp_add<CTRL, MASK>(s3); \
            s4 = dpp_add<CTRL, MASK>(s4); s5 = dpp_add<CTRL, MASK>(s5);
        STAGE(0x111, 0xf)   // row_shr:1
        STAGE(0x112, 0xf)   // row_shr:2
        STAGE(0x114, 0xf)   // row_shr:4
        STAGE(0x118, 0xf)   // row_shr:8
        STAGE(0x142, 0xa)   // row_bcast15 -> rows 1,3
        STAGE(0x143, 0xc)   // row_bcast31 -> rows 2,3 ; lane63 = wave total
        #undef STAGE
        if (lane == 63) {
            pp[0 * 8 + wid] = s0;
            pp[1 * 8 + wid] = s1;
            pp[2 * 8 + wid] = s2;
            pp[3 * 8 + wid] = s3;
            pp[4 * 8 + wid] = s4;
            pp[5 * 8 + wid] = s5;
        }
        BARW();
        // ---- phase B: wave 0 sums groups of 8 partials (within DPP rows) ----
        if (wid == 0) {
            float v = pp[lane];              // lanes 48-63 read junk, unused
            v = dpp_add<0x111, 0xf>(v);
            v = dpp_add<0x112, 0xf>(v);
            v = dpp_add<0x114, 0xf>(v);      // lanes 0,8,..,40 = group sums
            if ((lane & 7) == 0 && lane < 48) res[lane >> 3] = v;
        }
        BARW();
        // ---- phase C ----
        float4 r4 = *(const float4*)&res[0];   // a0,a1,m0,m1
        float2 r2 = *(const float2*)&res[4];   // n0,n1
        float rr = r4.x * tMr0 + r4.y * tMr1
                 + (r4.z * r2.x) * tLt0 + (r4.w * r2.y) * tLt1;
        x = (1.0f - kTau) * x + rr + c;
        tp[(size_t)t * kH] = x;
        int t2 = (t + 2) & (kT - 1);           // wrap at tail: value unused
        c = tp[(size_t)t2 * kH];
    };

    for (int t = 0; t < kT; t += 2) {
        step(t, cA);
        step(t + 1, cB);
    }
    xfin[b * kH + h] = x;
}

// ---------------------------------------------------------------------------
// out_kernel: out[row][o] = sum_h tanh(traj[row][h])*Wout_w[o][h] + Wout_b[o]
// 512 blocks x 256 thr; 256 rows/block; 16 chunks of 32 h. Double-buffered
// LDS + BARW: chunk ch+1's global loads stay in flight (vmcnt) under chunk
// ch's compute — no per-chunk vmcnt(0) drain. XCD-swizzled so each block
// reads traj rows written by a scan block on the SAME XCD (b%8 == g%8).
// ---------------------------------------------------------------------------
constexpr int R_BLK = 256;
constexpr int H_CHK = 32;
constexpr int AS_LD = 260;   // pad keeps rows 16B-aligned, reads ~2-way

__global__ __launch_bounds__(256, 2) void out_kernel(
    const float* __restrict__ traj, const float* __restrict__ Wout_w,
    const float* __restrict__ Wout_b, float* __restrict__ out)
{
    __shared__ float As[2][H_CHK][AS_LD];   // 66.6 KB
    __shared__ float Ws[2][H_CHK][36];      //  9.2 KB

    const int tid = threadIdx.x;
    // bijective XCD swizzle: logical l has (l/4)%8 == g%8 (= this block's XCD)
    const int g = blockIdx.x;
    const int l = (g & 7) * 4 + ((g >> 3) & 3) + ((g >> 5) << 5);
    const size_t row0 = (size_t)l * R_BLK;

    const int og = tid & 3;          // o-group: 8 outputs
    const int rg = tid >> 2;         // row-group: 4 rows
    const int lr = tid >> 3, lc4 = tid & 7;          // As staging
    const int wo = tid >> 3, wc = (tid & 7) * 4;     // Ws staging

    float acc[4][8];
    #pragma unroll
    for (int k = 0; k < 4; ++k)
        #pragma unroll
        for (int j = 0; j < 8; ++j) acc[k][j] = 0.f;

    float4 a[8];
    float4 w;
    // prologue: loads for chunk 0
    #pragma unroll
    for (int j = 0; j < 8; ++j)
        a[j] = *(const float4*)&traj[(row0 + j * 32 + lr) * kH + lc4 * 4];
    w = *(const float4*)&Wout_w[(size_t)wo * kH + wc];

    for (int ch = 0; ch < 16; ++ch) {
        const int p = ch & 1;
        // stage (compiler inserts vmcnt waits on a/w here)
        #pragma unroll
        for (int j = 0; j < 8; ++j) {
            const int rr = j * 32 + lr;
            As[p][lc4 * 4 + 0][rr] = fast_tanh(a[j].x);
            As[p][lc4 * 4 + 1][rr] = fast_tanh(a[j].y);
            As[p][lc4 * 4 + 2][rr] = fast_tanh(a[j].z);
            As[p][lc4 * 4 + 3][rr] = fast_tanh(a[j].w);
        }
        Ws[p][wc + 0][wo] = w.x;
        Ws[p][wc + 1][wo] = w.y;
        Ws[p][wc + 2][wo] = w.z;
        Ws[p][wc + 3][wo] = w.w;
        BARW();
        // issue next chunk's loads; they fly under this chunk's compute
        if (ch < 15) {
            const int hc = (ch + 1) * H_CHK;
            #pragma unroll
            for (int j = 0; j < 8; ++j)
                a[j] = *(const float4*)
                    &traj[(row0 + j * 32 + lr) * kH + hc + lc4 * 4];
            w = *(const float4*)&Wout_w[(size_t)wo * kH + hc + wc];
        }
        #pragma unroll
        for (int hh = 0; hh < H_CHK; ++hh) {
            float4 av = *(const float4*)&As[p][hh][rg * 4];
            float4 w0 = *(const float4*)&Ws[p][hh][og * 8];
            float4 w1 = *(const float4*)&Ws[p][hh][og * 8 + 4];
            const float av4[4] = {av.x, av.y, av.z, av.w};
            const float wv[8]  = {w0.x, w0.y, w0.z, w0.w,
                                  w1.x, w1.y, w1.z, w1.w};
            #pragma unroll
            for (int k = 0; k < 4; ++k)
                #pragma unroll
                for (int j = 0; j < 8; ++j)
                    acc[k][j] += av4[k] * wv[j];
        }
        BARW();
    }

    #pragma unroll
    for (int k = 0; k < 4; ++k) {
        const size_t row = row0 + rg * 4 + k;
        float4 v0, v1;
        v0.x = acc[k][0] + Wout_b[og * 8 + 0];
        v0.y = acc[k][1] + Wout_b[og * 8 + 1];
        v0.z = acc[k][2] + Wout_b[og * 8 + 2];
        v0.w = acc[k][3] + Wout_b[og * 8 + 3];
        v1.x = acc[k][4] + Wout_b[og * 8 + 4];
        v1.y = acc[k][5] + Wout_b[og * 8 + 5];
        v1.z = acc[k][6] + Wout_b[og * 8 + 6];
        v1.w = acc[k][7] + Wout_b[og * 8 + 7];
        *(float4*)&out[row * kO + og * 8]     = v0;
        *(float4*)&out[row * kO + og * 8 + 4] = v1;
    }
}

extern "C" void kernel_launch(void* const* d_in, const int* in_sizes, int n_in,
                              void* d_out, int out_size, void* d_ws, size_t ws_size,
                              hipStream_t stream) {
    const float* u      = (const float*)d_in[0];
    const float* x0     = (const float*)d_in[1];
    const float* noise  = (const float*)d_in[2];
    const float* Win_w  = (const float*)d_in[3];
    const float* Win_b  = (const float*)d_in[4];
    const float* Wout_w = (const float*)d_in[5];
    const float* Wout_b = (const float*)d_in[6];
    const float* M_rnn  = (const float*)d_in[7];
    const float* N_rnn  = (const float*)d_in[8];
    const float* L_tb   = (const float*)d_in[9];
    const float* M_tb   = (const float*)d_in[10];
    const float* N_tb   = (const float*)d_in[11];

    float* out  = (float*)d_out;                       // [B,T,O]
    float* xfin = out + (size_t)kB * kT * kO;          // [B,H]
    float* traj = xfin + (size_t)kB * kH;              // [B,T,H]

    inp_kernel<<<dim3((kB * kT) / ROWS_PB), dim3(256), 0, stream>>>(
        u, Win_w, Win_b, noise, traj);
    scan_kernel<<<dim3(kB), dim3(kH), 0, stream>>>(
        x0, M_rnn, N_rnn, L_tb, M_tb, N_tb, traj, xfin);
    out_kernel<<<dim3((kB * kT) / R_BLK), dim3(256), 0, stream>>>(
        traj, Wout_w, Wout_b, out);
}